// Round 20
// baseline (151.383 us; speedup 1.0000x reference)
//
#include <hip/hip_runtime.h>
#include <hip/hip_bf16.h>

#define BLK 256
#define SCAT_NB 512        // blocks in the binning scatter pass
#define BIN_SHIFT 8        // 256 nodes per bin
#define STAGE_CAP 6144     // LDS-staged edges per bin (mean ~4080, 19-sigma headroom)

typedef unsigned short ushort_t;
typedef unsigned int uint_t;
typedef unsigned long long ull_t;
typedef __attribute__((ext_vector_type(8))) short bf16x8;
typedef __attribute__((ext_vector_type(8))) unsigned short ushort8_t;
typedef __attribute__((ext_vector_type(4))) float f32x4;

static __device__ __forceinline__ float bf2f(ushort_t u) {
    return __uint_as_float((uint_t)u << 16);
}
static __device__ __forceinline__ ushort_t f2bf(float f) {
    __hip_bfloat16 h = __float2bfloat16(f);   // RNE
    return *reinterpret_cast<ushort_t*>(&h);
}

// ================= structure (R19) =================
// R19 counters: timed replays are fully cache-resident (6.4MB HBM) yet fused1
// still takes 43us -> pure concurrency-limited latency. R20: 2-deep software
// pipeline of the H-row gathers themselves (rotated A/B register sets, manual
// 2x unroll, no register copies, single edge pointer). While FMAs consume
// batch A, batch B's indices AND gathers are in flight.

// ---------------- fused prologue: bin_count + weight conv ----------------

__global__ __launch_bounds__(256) void k_pre(const int* __restrict__ eidx,
                                             int* __restrict__ bcnt,
                                             int nbins, int epb, int E,
                                             const float* __restrict__ W1, ushort_t* __restrict__ Wt1,
                                             const float* __restrict__ W2, ushort_t* __restrict__ Wt2,
                                             const float* __restrict__ W3, ushort_t* __restrict__ Wt3) {
    const int b = blockIdx.x;
    const int t = threadIdx.x;
    if (b < SCAT_NB) {
        __shared__ int h[256];
        h[t] = 0;
        __syncthreads();
        const int base = b * epb;
        const int lim  = min(base + epb, E);
        for (int e = base + t; e < lim; e += 256)
            atomicAdd(&h[eidx[E + e] >> BIN_SHIFT], 1);
        __syncthreads();
        if (t < nbins) bcnt[(size_t)t * SCAT_NB + b] = h[t];
    } else {
        int j = (b - SCAT_NB) * 256 + t;   // W[fin][fout] -> Wt[fout][fin] bf16
        if (j < 128 * 128) {
            int r = j / 128, c = j % 128;
            Wt1[(size_t)c * 128 + r] = f2bf(W1[j]);
        } else if (j < 128 * 128 + 128 * 64) {
            j -= 128 * 128;
            int r = j / 64, c = j % 64;
            Wt2[(size_t)c * 128 + r] = f2bf(W2[j]);
        } else if (j < 128 * 128 + 128 * 64 + 64 * 32) {
            j -= 128 * 128 + 128 * 64;
            int r = j / 32, c = j % 32;
            Wt3[(size_t)c * 64 + r] = f2bf(W3[j]);
        }
    }
}

// ---------------- scans for the bin-offset table ----------------

__global__ __launch_bounds__(256) void k_scan1(const int* __restrict__ cnt,
                                               int* rowptr, int* bsum, int n) {
    __shared__ int tile[256];
    const int t = threadIdx.x;
    const int i = blockIdx.x * 256 + t;
    int v = (i < n) ? cnt[i] : 0;
    tile[t] = v;
    __syncthreads();
    for (int off = 1; off < 256; off <<= 1) {
        int x = (t >= off) ? tile[t - off] : 0;
        __syncthreads();
        tile[t] += x;
        __syncthreads();
    }
    if (i < n) rowptr[i] = tile[t] - v;
    if (t == 255) bsum[blockIdx.x] = tile[255];
}

// single block, arbitrary n (serial tiles with carry), in-place exclusive
__global__ __launch_bounds__(256) void k_scan2x(int* a, int n) {
    __shared__ int tile[256];
    __shared__ int carry_s;
    const int t = threadIdx.x;
    if (t == 0) carry_s = 0;
    __syncthreads();
    for (int base = 0; base < n; base += 256) {
        int i = base + t;
        int v = (i < n) ? a[i] : 0;
        tile[t] = v;
        __syncthreads();
        for (int off = 1; off < 256; off <<= 1) {
            int x = (t >= off) ? tile[t - off] : 0;
            __syncthreads();
            tile[t] += x;
            __syncthreads();
        }
        int carry = carry_s;
        if (i < n) a[i] = carry + tile[t] - v;
        __syncthreads();
        if (t == 255) carry_s = carry + tile[255];
        __syncthreads();
    }
}

// consumers reconstruct global offsets as ebofs[idx] + bsumB[idx>>8]

// ---------------- binned edge scatter (8B packed: (s<<8)|(d&255), w) ----------------

__global__ __launch_bounds__(256) void k_bin_scatter(const int* __restrict__ eidx,
                                                     const float* __restrict__ ea,
                                                     const int* __restrict__ ebofs,
                                                     const int* __restrict__ bsumB,
                                                     uint2* __restrict__ binned,
                                                     int nbins, int epb, int E) {
    __shared__ int h[256];
    __shared__ int lofs[256];
    const int t = threadIdx.x;
    h[t] = 0;
    if (t < nbins) {
        int idx = t * SCAT_NB + blockIdx.x;
        lofs[t] = ebofs[idx] + bsumB[idx >> 8];
    }
    __syncthreads();
    const int base = blockIdx.x * epb;
    const int lim  = min(base + epb, E);
    for (int e = base + t; e < lim; e += 256) {
        int s = eidx[e];
        int d = eidx[E + e];
        float w = ea[e];
        int bin = d >> BIN_SHIFT;
        int r = atomicAdd(&h[bin], 1);      // LDS-local rank
        int pos = lofs[bin] + r;
        binned[pos] = make_uint2(((uint_t)s << 8) | (uint_t)(d & 255), __float_as_uint(w));
    }
}

// ---------------- fused per-bin hist + rowptr + dinv + CSR emit ----------------

__global__ __launch_bounds__(256) void k_bin_finish(const uint2* __restrict__ binned,
                                                    const int* __restrict__ ebofs,
                                                    const int* __restrict__ bsumB,
                                                    float* __restrict__ dinv,
                                                    int* __restrict__ rowptr,
                                                    int* __restrict__ csr_src,
                                                    float* __restrict__ csr_val,
                                                    int nbins, int N, int E) {
    __shared__ uint2 stage[STAGE_CAP];   // 48 KB
    __shared__ ull_t hs[256];
    __shared__ int   sc[256];
    __shared__ int   rp[256];
    __shared__ float dl[256];
    __shared__ int   c2[256];
    const int t = threadIdx.x;
    const int b = blockIdx.x;
    hs[t] = 0ull;
    c2[t] = 0;
    __syncthreads();
    const int i0 = b * SCAT_NB;
    const int start = ebofs[i0] + bsumB[i0 >> 8];
    int end = E;
    if (b + 1 < nbins) {
        int i1 = (b + 1) * SCAT_NB;
        end = ebofs[i1] + bsumB[i1 >> 8];
    }
    const int cnt = end - start;
    const bool fits = (cnt <= STAGE_CAP);

    if (fits) {
        for (int i = t; i < cnt; i += 256) {
            uint2 p = binned[start + i];
            stage[i] = p;
            atomicAdd(&hs[p.x & 255],
                      (1ull << 40) | (ull_t)(__uint_as_float(p.y) * 4294967296.0f));
        }
    } else {
        for (int i = start + t; i < end; i += 256) {
            uint2 p = binned[i];
            atomicAdd(&hs[p.x & 255],
                      (1ull << 40) | (ull_t)(__uint_as_float(p.y) * 4294967296.0f));
        }
    }
    __syncthreads();

    int v = (int)(hs[t] >> 40);
    sc[t] = v;
    __syncthreads();
    for (int off = 1; off < 256; off <<= 1) {
        int x = (t >= off) ? sc[t - off] : 0;
        __syncthreads();
        sc[t] += x;
        __syncthreads();
    }
    {
        ull_t s = hs[t];
        float dg = 1.0f + (float)(s & ((1ull << 40) - 1)) * (1.0f / 4294967296.0f);
        float di = rsqrtf(dg);
        dl[t] = di;
        rp[t] = start + sc[t] - v;
        const int node = (b << BIN_SHIFT) + t;
        if (node < N) {
            dinv[node]   = di;
            rowptr[node] = rp[t];
        }
        if (b == 0 && t == 0) rowptr[N] = E;
    }
    __syncthreads();

    if (fits) {
        for (int i = t; i < cnt; i += 256) {
            uint2 p = stage[i];
            int d8 = p.x & 255;
            int r = atomicAdd(&c2[d8], 1);
            int pos = rp[d8] + r;
            csr_src[pos] = (int)(p.x >> 8);
            csr_val[pos] = __uint_as_float(p.y) * dl[d8];
        }
    } else {
        for (int i = start + t; i < end; i += 256) {
            uint2 p = binned[i];
            int d8 = p.x & 255;
            int r = atomicAdd(&c2[d8], 1);
            int pos = rp[d8] + r;
            csr_src[pos] = (int)(p.x >> 8);
            csr_val[pos] = __uint_as_float(p.y) * dl[d8];
        }
    }
}

// ---------------- gather-accumulate body: 2-deep gather pipeline ----------------

#define ACC8(vj, mj)                                                              \
    { a[0] += vj * bf2f(mj[0]); a[1] += vj * bf2f(mj[1]);                         \
      a[2] += vj * bf2f(mj[2]); a[3] += vj * bf2f(mj[3]);                         \
      a[4] += vj * bf2f(mj[4]); a[5] += vj * bf2f(mj[5]);                         \
      a[6] += vj * bf2f(mj[6]); a[7] += vj * bf2f(mj[7]); }

#define LOADI(pfx, base)                                                          \
    int pfx##0 = csr_src[(base)+0], pfx##1 = csr_src[(base)+1],                   \
        pfx##2 = csr_src[(base)+2], pfx##3 = csr_src[(base)+3],                   \
        pfx##4 = csr_src[(base)+4], pfx##5 = csr_src[(base)+5],                   \
        pfx##6 = csr_src[(base)+6], pfx##7 = csr_src[(base)+7];

#define GATHER(dst, pfx)                                                          \
    ushort8_t dst##0 = *(const ushort8_t*)(Hf + (size_t)pfx##0 * FIN);            \
    ushort8_t dst##1 = *(const ushort8_t*)(Hf + (size_t)pfx##1 * FIN);            \
    ushort8_t dst##2 = *(const ushort8_t*)(Hf + (size_t)pfx##2 * FIN);            \
    ushort8_t dst##3 = *(const ushort8_t*)(Hf + (size_t)pfx##3 * FIN);            \
    ushort8_t dst##4 = *(const ushort8_t*)(Hf + (size_t)pfx##4 * FIN);            \
    ushort8_t dst##5 = *(const ushort8_t*)(Hf + (size_t)pfx##5 * FIN);            \
    ushort8_t dst##6 = *(const ushort8_t*)(Hf + (size_t)pfx##6 * FIN);            \
    ushort8_t dst##7 = *(const ushort8_t*)(Hf + (size_t)pfx##7 * FIN);

#define REGATHER(dst, pfx)                                                        \
    dst##0 = *(const ushort8_t*)(Hf + (size_t)pfx##0 * FIN);                      \
    dst##1 = *(const ushort8_t*)(Hf + (size_t)pfx##1 * FIN);                      \
    dst##2 = *(const ushort8_t*)(Hf + (size_t)pfx##2 * FIN);                      \
    dst##3 = *(const ushort8_t*)(Hf + (size_t)pfx##3 * FIN);                      \
    dst##4 = *(const ushort8_t*)(Hf + (size_t)pfx##4 * FIN);                      \
    dst##5 = *(const ushort8_t*)(Hf + (size_t)pfx##5 * FIN);                      \
    dst##6 = *(const ushort8_t*)(Hf + (size_t)pfx##6 * FIN);                      \
    dst##7 = *(const ushort8_t*)(Hf + (size_t)pfx##7 * FIN);

#define CONSUME(dst, base)                                                        \
    { float v0 = csr_val[(base)+0], v1 = csr_val[(base)+1],                       \
            v2 = csr_val[(base)+2], v3 = csr_val[(base)+3],                       \
            v4 = csr_val[(base)+4], v5 = csr_val[(base)+5],                       \
            v6 = csr_val[(base)+6], v7 = csr_val[(base)+7];                       \
      ACC8(v0, dst##0); ACC8(v1, dst##1); ACC8(v2, dst##2); ACC8(v3, dst##3);     \
      ACC8(v4, dst##4); ACC8(v5, dst##5); ACC8(v6, dst##6); ACC8(v7, dst##7); }

template <int FIN>
static __device__ __forceinline__ void agg_body(const ushort_t* __restrict__ Hf,
                                                const int* __restrict__ csr_src,
                                                const float* __restrict__ csr_val,
                                                int e0, int e1, float* a /*[8]*/) {
    int e = e0;
    const int nb = (e1 - e0) >> 3;
    if (nb > 0) {
        // prime batch A (indices + gathers in flight)
        LOADI(sa, e)
        GATHER(mA, sa)
        int b = 1;
        for (; b + 1 < nb; b += 2) {
            // issue batch B (e+8), then consume A
            LOADI(sb, e + 8)
            GATHER(mB, sb)
            CONSUME(mA, e)
            // issue next batch into A (e+16), then consume B
            LOADI(sc2, e + 16)
            REGATHER(mA, sc2)
            CONSUME(mB, e + 8)
            e += 16;
        }
        if (b < nb) {   // exactly one more full batch beyond A
            LOADI(sb, e + 8)
            GATHER(mB, sb)
            CONSUME(mA, e)
            CONSUME(mB, e + 8)
            e += 16;
        } else {        // only A remains
            CONSUME(mA, e)
            e += 8;
        }
    }
    for (; e + 2 <= e1; e += 2) {
        int   s0 = csr_src[e+0], s1 = csr_src[e+1];
        float v0 = csr_val[e+0], v1 = csr_val[e+1];
        ushort8_t m0 = *(const ushort8_t*)(Hf + (size_t)s0 * FIN);
        ushort8_t m1 = *(const ushort8_t*)(Hf + (size_t)s1 * FIN);
        ACC8(v0, m0); ACC8(v1, m1);
    }
    if (e < e1) {
        int   s0 = csr_src[e];
        float v0 = csr_val[e];
        ushort8_t m0 = *(const ushort8_t*)(Hf + (size_t)s0 * FIN);
        ACC8(v0, m0);
    }
}

// ---------------- FUSED agg + gemm: G = relu(agg(H')+b); C = dinv*(G @ Wt^T) ----------------

template <int FIN, int FOUT>
__global__ __launch_bounds__(256) void k_agg_gemm(const ushort_t* __restrict__ H,
                                                  const float* __restrict__ dinv,
                                                  const int* __restrict__ rowptr,
                                                  const int* __restrict__ csr_src,
                                                  const float* __restrict__ csr_val,
                                                  const float* __restrict__ bias,
                                                  const ushort_t* __restrict__ Wt,
                                                  ushort_t* __restrict__ C, int n) {
    constexpr int PAD = 8;
    __shared__ ushort_t Gs[32][FIN + PAD];
    constexpr int LPN = FIN / 8;       // lanes per node: 16 / 8
    constexpr int NPW = 64 / LPN;      // nodes per wave: 4 / 8
    constexpr int NPB = NPW * 4;       // nodes per block pass: 16 / 32
    constexpr int NPASS = 32 / NPB;    // 2 / 1
    constexpr int NT = FOUT / 16;      // col tiles: 4 / 2
    constexpr int NK = FIN / 32;       // K steps: 4 / 2

    const int wave = threadIdx.x >> 6;
    const int lane = threadIdx.x & 63;
    const int r0 = blockIdx.x * 32;
    const int sub = lane / LPN;
    const int f8  = lane % LPN;
    const ushort_t* __restrict__ Hf = H + 8 * f8;

    // ---- phase A: aggregate 32 nodes into LDS ----
#pragma unroll
    for (int p = 0; p < NPASS; ++p) {
        const int nb = p * NPB + wave * NPW + sub;
        const int node = r0 + nb;
        float a[8] = {};
        if (node < n) {
            const float sn = dinv[node];
            ushort8_t hv = *(const ushort8_t*)(Hf + (size_t)node * FIN);
#pragma unroll
            for (int k = 0; k < 8; ++k) a[k] = sn * bf2f(hv[k]);
            agg_body<FIN>(Hf, csr_src, csr_val, rowptr[node], rowptr[node + 1], a);
            float4 bv0 = *(const float4*)(bias + 8 * f8);
            float4 bv1 = *(const float4*)(bias + 8 * f8 + 4);
            a[0] = fmaxf(a[0] + bv0.x, 0.f); a[1] = fmaxf(a[1] + bv0.y, 0.f);
            a[2] = fmaxf(a[2] + bv0.z, 0.f); a[3] = fmaxf(a[3] + bv0.w, 0.f);
            a[4] = fmaxf(a[4] + bv1.x, 0.f); a[5] = fmaxf(a[5] + bv1.y, 0.f);
            a[6] = fmaxf(a[6] + bv1.z, 0.f); a[7] = fmaxf(a[7] + bv1.w, 0.f);
        }
        ushort8_t o;
#pragma unroll
        for (int k = 0; k < 8; ++k) o[k] = f2bf(a[k]);
        *(ushort8_t*)(&Gs[nb][8 * f8]) = o;
    }
    __syncthreads();

    // ---- phase B: 32-row MFMA from LDS ----
    const int l15 = lane & 15;
    const int kg  = lane >> 4;
    for (int item = wave; item < 2 * NT; item += 4) {
        const int g  = item / NT;      // row group
        const int ct = item % NT;      // col tile
        f32x4 acc = (f32x4)(0.0f);
        const ushort_t* Bp = Wt + (size_t)(ct * 16 + l15) * FIN + kg * 8;
        const int arow = g * 16 + l15;
#pragma unroll
        for (int ks = 0; ks < NK; ++ks) {
            bf16x8 av = *(const bf16x8*)(&Gs[arow][kg * 8 + ks * 32]);
            bf16x8 bv = *(const bf16x8*)(Bp + ks * 32);
            acc = __builtin_amdgcn_mfma_f32_16x16x32_bf16(av, bv, acc, 0, 0, 0);
        }
        const int rbase = r0 + g * 16 + kg * 4;
#pragma unroll
        for (int j = 0; j < 4; ++j) {
            int row = rbase + j;
            if (row < n)
                C[(size_t)row * FOUT + ct * 16 + l15] = f2bf(acc[j] * dinv[row]);
        }
    }
}

// ---------------- MFMA GEMM (layer 1): C = dinv * (x(f32) @ Wt^T) ----------------

template <int FIN, int FOUT>
__global__ __launch_bounds__(256) void k_gemm_f32(const float* __restrict__ A,
                                                  const ushort_t* __restrict__ Wt,
                                                  const float* __restrict__ dinv,
                                                  ushort_t* __restrict__ C, int n) {
    constexpr int NT = FOUT / 16;
    constexpr int NK = FIN / 32;
    const int wave = threadIdx.x >> 6;
    const int lane = threadIdx.x & 63;
    const int r0 = (blockIdx.x * 4 + wave) * 32;
    if (r0 >= n) return;

    const int l15 = lane & 15;
    const int kg  = lane >> 4;
    const int arow0 = min(r0 + l15, n - 1);
    const int arow1 = min(r0 + 16 + l15, n - 1);

    f32x4 acc0[NT], acc1[NT];
#pragma unroll
    for (int c = 0; c < NT; ++c) { acc0[c] = (f32x4)(0.0f); acc1[c] = (f32x4)(0.0f); }

    const ushort_t* Bp = Wt + (size_t)l15 * FIN + kg * 8;

#pragma unroll 1   // keep rolled: full unroll hoists all B loads -> spill (R1 lesson)
    for (int ks = 0; ks < NK; ++ks) {
        bf16x8 a0, a1;
        const float* p0 = A + (size_t)arow0 * FIN + kg * 8 + ks * 32;
        const float* p1 = A + (size_t)arow1 * FIN + kg * 8 + ks * 32;
        float4 u0 = *(const float4*)p0, u1 = *(const float4*)(p0 + 4);
        float4 w0 = *(const float4*)p1, w1 = *(const float4*)(p1 + 4);
        a0[0] = (short)f2bf(u0.x); a0[1] = (short)f2bf(u0.y);
        a0[2] = (short)f2bf(u0.z); a0[3] = (short)f2bf(u0.w);
        a0[4] = (short)f2bf(u1.x); a0[5] = (short)f2bf(u1.y);
        a0[6] = (short)f2bf(u1.z); a0[7] = (short)f2bf(u1.w);
        a1[0] = (short)f2bf(w0.x); a1[1] = (short)f2bf(w0.y);
        a1[2] = (short)f2bf(w0.z); a1[3] = (short)f2bf(w0.w);
        a1[4] = (short)f2bf(w1.x); a1[5] = (short)f2bf(w1.y);
        a1[6] = (short)f2bf(w1.z); a1[7] = (short)f2bf(w1.w);
#pragma unroll
        for (int c = 0; c < NT; ++c) {
            bf16x8 bfr = *(const bf16x8*)(Bp + (size_t)c * 16 * FIN + ks * 32);
            acc0[c] = __builtin_amdgcn_mfma_f32_16x16x32_bf16(a0, bfr, acc0[c], 0, 0, 0);
            acc1[c] = __builtin_amdgcn_mfma_f32_16x16x32_bf16(a1, bfr, acc1[c], 0, 0, 0);
        }
    }

#pragma unroll
    for (int g = 0; g < 2; ++g) {
        const int rbase = r0 + g * 16 + kg * 4;
#pragma unroll
        for (int j = 0; j < 4; ++j) {
            int row = rbase + j;
            if (row < n) {
                float dscale = dinv[row];
#pragma unroll
                for (int c = 0; c < NT; ++c) {
                    float val = (g == 0) ? acc0[c][j] : acc1[c][j];
                    C[(size_t)row * FOUT + c * 16 + l15] = f2bf(val * dscale);
                }
            }
        }
    }
}

// ---------------- final aggregation (layer 3, f32 out, no relu) ----------------

template <int FIN>
__global__ __launch_bounds__(256) void k_agg_final(const ushort_t* __restrict__ H,
                                                   const float* __restrict__ dinv,
                                                   const int* __restrict__ rowptr,
                                                   const int* __restrict__ csr_src,
                                                   const float* __restrict__ csr_val,
                                                   const float* __restrict__ bias,
                                                   float* __restrict__ out, int n) {
    constexpr int LPN = FIN / 8;       // 4 lanes per node
    constexpr int NPW = 64 / LPN;      // 16 nodes per wave
    const int wave = threadIdx.x >> 6;
    const int lane = threadIdx.x & 63;
    const int sub  = lane / LPN;
    const int f8   = lane % LPN;
    const int node = (blockIdx.x * 4 + wave) * NPW + sub;
    if (node >= n) return;

    const ushort_t* __restrict__ Hf = H + 8 * f8;
    const float sn = dinv[node];
    ushort8_t hv = *(const ushort8_t*)(Hf + (size_t)node * FIN);
    float a[8];
#pragma unroll
    for (int k = 0; k < 8; ++k) a[k] = sn * bf2f(hv[k]);

    agg_body<FIN>(Hf, csr_src, csr_val, rowptr[node], rowptr[node + 1], a);

    float4 bv0 = *(const float4*)(bias + 8 * f8);
    float4 bv1 = *(const float4*)(bias + 8 * f8 + 4);
    a[0] += bv0.x; a[1] += bv0.y; a[2] += bv0.z; a[3] += bv0.w;
    a[4] += bv1.x; a[5] += bv1.y; a[6] += bv1.z; a[7] += bv1.w;
    float* op = out + (size_t)node * FIN + 8 * f8;
    *(float4*)op       = make_float4(a[0], a[1], a[2], a[3]);
    *(float4*)(op + 4) = make_float4(a[4], a[5], a[6], a[7]);
}

// ---------------- launch ----------------

extern "C" void kernel_launch(void* const* d_in, const int* in_sizes, int n_in,
                              void* d_out, int out_size, void* d_ws, size_t ws_size,
                              hipStream_t stream) {
    const float* x    = (const float*)d_in[0];
    const int*   eidx = (const int*)d_in[1];
    const float* ea   = (const float*)d_in[2];
    const float* W1   = (const float*)d_in[3];
    const float* b1   = (const float*)d_in[4];
    const float* W2   = (const float*)d_in[5];
    const float* b2   = (const float*)d_in[6];
    const float* W3   = (const float*)d_in[7];
    const float* b3   = (const float*)d_in[8];

    const int N = in_sizes[0] / 128;
    const int E = in_sizes[2];

    const int nbins = (N + 255) >> BIN_SHIFT;            // 196 for N=50000 (<=256)
    const int epb   = (E + SCAT_NB - 1) / SCAT_NB;       // edges per scatter block
    const int nbc   = nbins * SCAT_NB;                   // bcnt/ebofs length
    const int gBC   = (nbc + BLK - 1) / BLK;

    char*  base = (char*)d_ws;
    size_t off  = 0;
    auto carve = [&](size_t nbytes) -> void* {
        void* p = base + off;
        off = (off + nbytes + 255) & ~(size_t)255;
        return p;
    };
    int*   bcnt      = (int*)  carve((size_t)nbc * 4);
    int*   ebofs     = (int*)  carve((size_t)nbc * 4);
    int*   bsumB     = (int*)  carve((size_t)512 * 4);
    uint2* binned    = (uint2*)carve((size_t)E * 8);
    float* dinv      = (float*)carve((size_t)N * 4);
    int*   rowptr    = (int*)  carve((size_t)(N + 1) * 4);
    int*   csr_src   = (int*)  carve((size_t)E * 4);
    float* csr_val   = (float*)carve((size_t)E * 4);
    ushort_t* bufA   = (ushort_t*)carve((size_t)N * 128 * 2);   // bf16: H'1 / H'3
    ushort_t* bufB   = (ushort_t*)carve((size_t)N * 64 * 2);    // bf16: H'2
    ushort_t* Wt1    = (ushort_t*)carve((size_t)128 * 128 * 2);
    ushort_t* Wt2    = (ushort_t*)carve((size_t)64 * 128 * 2);
    ushort_t* Wt3    = (ushort_t*)carve((size_t)32 * 64 * 2);
    (void)ws_size;

    const int wtot = 128 * 128 + 128 * 64 + 64 * 32;
    const int gPre = SCAT_NB + (wtot + 255) / 256;
    const int gR  = (N + 127) / 128;                     // gemm1 blocks (128 rows/block)
    const int gF  = (N + 31) / 32;                       // fused agg+gemm blocks (32 rows)

    // preprocessing (5 dispatches, scan-based, no global atomics)
    k_pre<<<gPre, BLK, 0, stream>>>(eidx, bcnt, nbins, epb, E, W1, Wt1, W2, Wt2, W3, Wt3);
    k_scan1<<<gBC, BLK, 0, stream>>>(bcnt, ebofs, bsumB, nbc);
    k_scan2x<<<1, BLK, 0, stream>>>(bsumB, gBC);
    k_bin_scatter<<<SCAT_NB, BLK, 0, stream>>>(eidx, ea, ebofs, bsumB, binned, nbins, epb, E);
    k_bin_finish<<<nbins, BLK, 0, stream>>>(binned, ebofs, bsumB, dinv, rowptr,
                                            csr_src, csr_val, nbins, N, E);

    // layer 1 GEMM: H'1 = dinv * (x @ W1)   (reads f32 x directly)
    k_gemm_f32<128, 128><<<gR, BLK, 0, stream>>>(x, Wt1, dinv, bufA, N);

    // fused: G2 = relu(agg(H'1)+b1); H'2 = dinv*(G2 @ W2)
    k_agg_gemm<128, 64><<<gF, BLK, 0, stream>>>(bufA, dinv, rowptr, csr_src, csr_val,
                                                b1, Wt2, bufB, N);

    // fused: G3 = relu(agg(H'2)+b2); H'3 = dinv*(G3 @ W3)
    k_agg_gemm<64, 32><<<gF, BLK, 0, stream>>>(bufB, dinv, rowptr, csr_src, csr_val,
                                               b2, Wt3, bufA, N);

    // final: out = agg(H'3) + b3   (f32, no relu)
    k_agg_final<32><<<(N + 63) / 64, BLK, 0, stream>>>(bufA, dinv, rowptr, csr_src, csr_val,
                                                       b3, (float*)d_out, N);
}

// Round 21
// 129.513 us; speedup vs baseline: 1.1689x; 1.1689x over previous
//
#include <hip/hip_runtime.h>
#include <hip/hip_bf16.h>

#define BLK 256
#define SCAT_NB 512        // blocks in the binning scatter pass
#define BIN_SHIFT 8        // 256 nodes per bin
#define STAGE_CAP 6144     // LDS-staged edges per bin (mean ~4080, 19-sigma headroom)

typedef unsigned short ushort_t;
typedef unsigned int uint_t;
typedef unsigned long long ull_t;
typedef __attribute__((ext_vector_type(8))) short bf16x8;
typedef __attribute__((ext_vector_type(8))) unsigned short ushort8_t;
typedef __attribute__((ext_vector_type(4))) float f32x4;

static __device__ __forceinline__ float bf2f(ushort_t u) {
    return __uint_as_float((uint_t)u << 16);
}
static __device__ __forceinline__ ushort_t f2bf(float f) {
    __hip_bfloat16 h = __float2bfloat16(f);   // RNE
    return *reinterpret_cast<ushort_t*>(&h);
}

// ================= structure (R20 post-mortem) =================
// Gather-concurrency experiments, settled: R17 dual-stream (-24us), R19
// src-index prefetch (+2.3us), R20 2-deep gather pipeline (-21us). In-lane
// pipelining beyond the index stream loses to occupancy on this compiler.
// This is the R19 optimum: ushort8 gathers, src-index prefetch only, VGPR<=60.

// ---------------- fused prologue: bin_count + weight conv ----------------

__global__ __launch_bounds__(256) void k_pre(const int* __restrict__ eidx,
                                             int* __restrict__ bcnt,
                                             int nbins, int epb, int E,
                                             const float* __restrict__ W1, ushort_t* __restrict__ Wt1,
                                             const float* __restrict__ W2, ushort_t* __restrict__ Wt2,
                                             const float* __restrict__ W3, ushort_t* __restrict__ Wt3) {
    const int b = blockIdx.x;
    const int t = threadIdx.x;
    if (b < SCAT_NB) {
        __shared__ int h[256];
        h[t] = 0;
        __syncthreads();
        const int base = b * epb;
        const int lim  = min(base + epb, E);
        for (int e = base + t; e < lim; e += 256)
            atomicAdd(&h[eidx[E + e] >> BIN_SHIFT], 1);
        __syncthreads();
        if (t < nbins) bcnt[(size_t)t * SCAT_NB + b] = h[t];
    } else {
        int j = (b - SCAT_NB) * 256 + t;   // W[fin][fout] -> Wt[fout][fin] bf16
        if (j < 128 * 128) {
            int r = j / 128, c = j % 128;
            Wt1[(size_t)c * 128 + r] = f2bf(W1[j]);
        } else if (j < 128 * 128 + 128 * 64) {
            j -= 128 * 128;
            int r = j / 64, c = j % 64;
            Wt2[(size_t)c * 128 + r] = f2bf(W2[j]);
        } else if (j < 128 * 128 + 128 * 64 + 64 * 32) {
            j -= 128 * 128 + 128 * 64;
            int r = j / 32, c = j % 32;
            Wt3[(size_t)c * 64 + r] = f2bf(W3[j]);
        }
    }
}

// ---------------- scans for the bin-offset table ----------------

__global__ __launch_bounds__(256) void k_scan1(const int* __restrict__ cnt,
                                               int* rowptr, int* bsum, int n) {
    __shared__ int tile[256];
    const int t = threadIdx.x;
    const int i = blockIdx.x * 256 + t;
    int v = (i < n) ? cnt[i] : 0;
    tile[t] = v;
    __syncthreads();
    for (int off = 1; off < 256; off <<= 1) {
        int x = (t >= off) ? tile[t - off] : 0;
        __syncthreads();
        tile[t] += x;
        __syncthreads();
    }
    if (i < n) rowptr[i] = tile[t] - v;
    if (t == 255) bsum[blockIdx.x] = tile[255];
}

// single block, arbitrary n (serial tiles with carry), in-place exclusive
__global__ __launch_bounds__(256) void k_scan2x(int* a, int n) {
    __shared__ int tile[256];
    __shared__ int carry_s;
    const int t = threadIdx.x;
    if (t == 0) carry_s = 0;
    __syncthreads();
    for (int base = 0; base < n; base += 256) {
        int i = base + t;
        int v = (i < n) ? a[i] : 0;
        tile[t] = v;
        __syncthreads();
        for (int off = 1; off < 256; off <<= 1) {
            int x = (t >= off) ? tile[t - off] : 0;
            __syncthreads();
            tile[t] += x;
            __syncthreads();
        }
        int carry = carry_s;
        if (i < n) a[i] = carry + tile[t] - v;
        __syncthreads();
        if (t == 255) carry_s = carry + tile[255];
        __syncthreads();
    }
}

// consumers reconstruct global offsets as ebofs[idx] + bsumB[idx>>8]

// ---------------- binned edge scatter (8B packed: (s<<8)|(d&255), w) ----------------

__global__ __launch_bounds__(256) void k_bin_scatter(const int* __restrict__ eidx,
                                                     const float* __restrict__ ea,
                                                     const int* __restrict__ ebofs,
                                                     const int* __restrict__ bsumB,
                                                     uint2* __restrict__ binned,
                                                     int nbins, int epb, int E) {
    __shared__ int h[256];
    __shared__ int lofs[256];
    const int t = threadIdx.x;
    h[t] = 0;
    if (t < nbins) {
        int idx = t * SCAT_NB + blockIdx.x;
        lofs[t] = ebofs[idx] + bsumB[idx >> 8];
    }
    __syncthreads();
    const int base = blockIdx.x * epb;
    const int lim  = min(base + epb, E);
    for (int e = base + t; e < lim; e += 256) {
        int s = eidx[e];
        int d = eidx[E + e];
        float w = ea[e];
        int bin = d >> BIN_SHIFT;
        int r = atomicAdd(&h[bin], 1);      // LDS-local rank
        int pos = lofs[bin] + r;
        binned[pos] = make_uint2(((uint_t)s << 8) | (uint_t)(d & 255), __float_as_uint(w));
    }
}

// ---------------- fused per-bin hist + rowptr + dinv + CSR emit ----------------

__global__ __launch_bounds__(256) void k_bin_finish(const uint2* __restrict__ binned,
                                                    const int* __restrict__ ebofs,
                                                    const int* __restrict__ bsumB,
                                                    float* __restrict__ dinv,
                                                    int* __restrict__ rowptr,
                                                    int* __restrict__ csr_src,
                                                    float* __restrict__ csr_val,
                                                    int nbins, int N, int E) {
    __shared__ uint2 stage[STAGE_CAP];   // 48 KB
    __shared__ ull_t hs[256];
    __shared__ int   sc[256];
    __shared__ int   rp[256];
    __shared__ float dl[256];
    __shared__ int   c2[256];
    const int t = threadIdx.x;
    const int b = blockIdx.x;
    hs[t] = 0ull;
    c2[t] = 0;
    __syncthreads();
    const int i0 = b * SCAT_NB;
    const int start = ebofs[i0] + bsumB[i0 >> 8];
    int end = E;
    if (b + 1 < nbins) {
        int i1 = (b + 1) * SCAT_NB;
        end = ebofs[i1] + bsumB[i1 >> 8];
    }
    const int cnt = end - start;
    const bool fits = (cnt <= STAGE_CAP);

    if (fits) {
        for (int i = t; i < cnt; i += 256) {
            uint2 p = binned[start + i];
            stage[i] = p;
            atomicAdd(&hs[p.x & 255],
                      (1ull << 40) | (ull_t)(__uint_as_float(p.y) * 4294967296.0f));
        }
    } else {
        for (int i = start + t; i < end; i += 256) {
            uint2 p = binned[i];
            atomicAdd(&hs[p.x & 255],
                      (1ull << 40) | (ull_t)(__uint_as_float(p.y) * 4294967296.0f));
        }
    }
    __syncthreads();

    int v = (int)(hs[t] >> 40);
    sc[t] = v;
    __syncthreads();
    for (int off = 1; off < 256; off <<= 1) {
        int x = (t >= off) ? sc[t - off] : 0;
        __syncthreads();
        sc[t] += x;
        __syncthreads();
    }
    {
        ull_t s = hs[t];
        float dg = 1.0f + (float)(s & ((1ull << 40) - 1)) * (1.0f / 4294967296.0f);
        float di = rsqrtf(dg);
        dl[t] = di;
        rp[t] = start + sc[t] - v;
        const int node = (b << BIN_SHIFT) + t;
        if (node < N) {
            dinv[node]   = di;
            rowptr[node] = rp[t];
        }
        if (b == 0 && t == 0) rowptr[N] = E;
    }
    __syncthreads();

    if (fits) {
        for (int i = t; i < cnt; i += 256) {
            uint2 p = stage[i];
            int d8 = p.x & 255;
            int r = atomicAdd(&c2[d8], 1);
            int pos = rp[d8] + r;
            csr_src[pos] = (int)(p.x >> 8);
            csr_val[pos] = __uint_as_float(p.y) * dl[d8];
        }
    } else {
        for (int i = start + t; i < end; i += 256) {
            uint2 p = binned[i];
            int d8 = p.x & 255;
            int r = atomicAdd(&c2[d8], 1);
            int pos = rp[d8] + r;
            csr_src[pos] = (int)(p.x >> 8);
            csr_val[pos] = __uint_as_float(p.y) * dl[d8];
        }
    }
}

// ---------------- gather-accumulate body (ushort8 + src-index software pipeline) ----

#define ACC8(vj, mj)                                                              \
    { a[0] += vj * bf2f(mj[0]); a[1] += vj * bf2f(mj[1]);                         \
      a[2] += vj * bf2f(mj[2]); a[3] += vj * bf2f(mj[3]);                         \
      a[4] += vj * bf2f(mj[4]); a[5] += vj * bf2f(mj[5]);                         \
      a[6] += vj * bf2f(mj[6]); a[7] += vj * bf2f(mj[7]); }

template <int FIN>
static __device__ __forceinline__ void agg_body(const ushort_t* __restrict__ Hf,
                                                const int* __restrict__ csr_src,
                                                const float* __restrict__ csr_val,
                                                int e0, int e1, float* a /*[8]*/) {
    int e = e0;
    const int nb = (e1 - e0) >> 3;
    if (nb > 0) {
        // prime: src indices of batch 0 in flight
        int s0 = csr_src[e+0], s1 = csr_src[e+1], s2 = csr_src[e+2], s3 = csr_src[e+3];
        int s4 = csr_src[e+4], s5 = csr_src[e+5], s6 = csr_src[e+6], s7 = csr_src[e+7];
        for (int b = 1; b < nb; ++b) {
            const int en = e + 8;
            // prefetch NEXT batch's src indices (hides the index round-trip)
            int t0 = csr_src[en+0], t1 = csr_src[en+1], t2 = csr_src[en+2], t3 = csr_src[en+3];
            int t4 = csr_src[en+4], t5 = csr_src[en+5], t6 = csr_src[en+6], t7 = csr_src[en+7];
            ushort8_t m0 = *(const ushort8_t*)(Hf + (size_t)s0 * FIN);
            ushort8_t m1 = *(const ushort8_t*)(Hf + (size_t)s1 * FIN);
            ushort8_t m2 = *(const ushort8_t*)(Hf + (size_t)s2 * FIN);
            ushort8_t m3 = *(const ushort8_t*)(Hf + (size_t)s3 * FIN);
            ushort8_t m4 = *(const ushort8_t*)(Hf + (size_t)s4 * FIN);
            ushort8_t m5 = *(const ushort8_t*)(Hf + (size_t)s5 * FIN);
            ushort8_t m6 = *(const ushort8_t*)(Hf + (size_t)s6 * FIN);
            ushort8_t m7 = *(const ushort8_t*)(Hf + (size_t)s7 * FIN);
            float v0 = csr_val[e+0], v1 = csr_val[e+1], v2 = csr_val[e+2], v3 = csr_val[e+3];
            float v4 = csr_val[e+4], v5 = csr_val[e+5], v6 = csr_val[e+6], v7 = csr_val[e+7];
            ACC8(v0, m0); ACC8(v1, m1); ACC8(v2, m2); ACC8(v3, m3);
            ACC8(v4, m4); ACC8(v5, m5); ACC8(v6, m6); ACC8(v7, m7);
            s0 = t0; s1 = t1; s2 = t2; s3 = t3;
            s4 = t4; s5 = t5; s6 = t6; s7 = t7;
            e = en;
        }
        {   // drain batch
            ushort8_t m0 = *(const ushort8_t*)(Hf + (size_t)s0 * FIN);
            ushort8_t m1 = *(const ushort8_t*)(Hf + (size_t)s1 * FIN);
            ushort8_t m2 = *(const ushort8_t*)(Hf + (size_t)s2 * FIN);
            ushort8_t m3 = *(const ushort8_t*)(Hf + (size_t)s3 * FIN);
            ushort8_t m4 = *(const ushort8_t*)(Hf + (size_t)s4 * FIN);
            ushort8_t m5 = *(const ushort8_t*)(Hf + (size_t)s5 * FIN);
            ushort8_t m6 = *(const ushort8_t*)(Hf + (size_t)s6 * FIN);
            ushort8_t m7 = *(const ushort8_t*)(Hf + (size_t)s7 * FIN);
            float v0 = csr_val[e+0], v1 = csr_val[e+1], v2 = csr_val[e+2], v3 = csr_val[e+3];
            float v4 = csr_val[e+4], v5 = csr_val[e+5], v6 = csr_val[e+6], v7 = csr_val[e+7];
            ACC8(v0, m0); ACC8(v1, m1); ACC8(v2, m2); ACC8(v3, m3);
            ACC8(v4, m4); ACC8(v5, m5); ACC8(v6, m6); ACC8(v7, m7);
            e += 8;
        }
    }
    for (; e + 2 <= e1; e += 2) {
        int   s0 = csr_src[e+0], s1 = csr_src[e+1];
        float v0 = csr_val[e+0], v1 = csr_val[e+1];
        ushort8_t m0 = *(const ushort8_t*)(Hf + (size_t)s0 * FIN);
        ushort8_t m1 = *(const ushort8_t*)(Hf + (size_t)s1 * FIN);
        ACC8(v0, m0); ACC8(v1, m1);
    }
    if (e < e1) {
        int   s0 = csr_src[e];
        float v0 = csr_val[e];
        ushort8_t m0 = *(const ushort8_t*)(Hf + (size_t)s0 * FIN);
        ACC8(v0, m0);
    }
}

// ---------------- FUSED agg + gemm: G = relu(agg(H')+b); C = dinv*(G @ Wt^T) ----------------

template <int FIN, int FOUT>
__global__ __launch_bounds__(256) void k_agg_gemm(const ushort_t* __restrict__ H,
                                                  const float* __restrict__ dinv,
                                                  const int* __restrict__ rowptr,
                                                  const int* __restrict__ csr_src,
                                                  const float* __restrict__ csr_val,
                                                  const float* __restrict__ bias,
                                                  const ushort_t* __restrict__ Wt,
                                                  ushort_t* __restrict__ C, int n) {
    constexpr int PAD = 8;
    __shared__ ushort_t Gs[32][FIN + PAD];
    constexpr int LPN = FIN / 8;       // lanes per node: 16 / 8
    constexpr int NPW = 64 / LPN;      // nodes per wave: 4 / 8
    constexpr int NPB = NPW * 4;       // nodes per block pass: 16 / 32
    constexpr int NPASS = 32 / NPB;    // 2 / 1
    constexpr int NT = FOUT / 16;      // col tiles: 4 / 2
    constexpr int NK = FIN / 32;       // K steps: 4 / 2

    const int wave = threadIdx.x >> 6;
    const int lane = threadIdx.x & 63;
    const int r0 = blockIdx.x * 32;
    const int sub = lane / LPN;
    const int f8  = lane % LPN;
    const ushort_t* __restrict__ Hf = H + 8 * f8;

    // ---- phase A: aggregate 32 nodes into LDS ----
#pragma unroll
    for (int p = 0; p < NPASS; ++p) {
        const int nb = p * NPB + wave * NPW + sub;
        const int node = r0 + nb;
        float a[8] = {};
        if (node < n) {
            const float sn = dinv[node];
            ushort8_t hv = *(const ushort8_t*)(Hf + (size_t)node * FIN);
#pragma unroll
            for (int k = 0; k < 8; ++k) a[k] = sn * bf2f(hv[k]);
            agg_body<FIN>(Hf, csr_src, csr_val, rowptr[node], rowptr[node + 1], a);
            float4 bv0 = *(const float4*)(bias + 8 * f8);
            float4 bv1 = *(const float4*)(bias + 8 * f8 + 4);
            a[0] = fmaxf(a[0] + bv0.x, 0.f); a[1] = fmaxf(a[1] + bv0.y, 0.f);
            a[2] = fmaxf(a[2] + bv0.z, 0.f); a[3] = fmaxf(a[3] + bv0.w, 0.f);
            a[4] = fmaxf(a[4] + bv1.x, 0.f); a[5] = fmaxf(a[5] + bv1.y, 0.f);
            a[6] = fmaxf(a[6] + bv1.z, 0.f); a[7] = fmaxf(a[7] + bv1.w, 0.f);
        }
        ushort8_t o;
#pragma unroll
        for (int k = 0; k < 8; ++k) o[k] = f2bf(a[k]);
        *(ushort8_t*)(&Gs[nb][8 * f8]) = o;
    }
    __syncthreads();

    // ---- phase B: 32-row MFMA from LDS ----
    const int l15 = lane & 15;
    const int kg  = lane >> 4;
    for (int item = wave; item < 2 * NT; item += 4) {
        const int g  = item / NT;      // row group
        const int ct = item % NT;      // col tile
        f32x4 acc = (f32x4)(0.0f);
        const ushort_t* Bp = Wt + (size_t)(ct * 16 + l15) * FIN + kg * 8;
        const int arow = g * 16 + l15;
#pragma unroll
        for (int ks = 0; ks < NK; ++ks) {
            bf16x8 av = *(const bf16x8*)(&Gs[arow][kg * 8 + ks * 32]);
            bf16x8 bv = *(const bf16x8*)(Bp + ks * 32);
            acc = __builtin_amdgcn_mfma_f32_16x16x32_bf16(av, bv, acc, 0, 0, 0);
        }
        const int rbase = r0 + g * 16 + kg * 4;
#pragma unroll
        for (int j = 0; j < 4; ++j) {
            int row = rbase + j;
            if (row < n)
                C[(size_t)row * FOUT + ct * 16 + l15] = f2bf(acc[j] * dinv[row]);
        }
    }
}

// ---------------- MFMA GEMM (layer 1): C = dinv * (x(f32) @ Wt^T) ----------------

template <int FIN, int FOUT>
__global__ __launch_bounds__(256) void k_gemm_f32(const float* __restrict__ A,
                                                  const ushort_t* __restrict__ Wt,
                                                  const float* __restrict__ dinv,
                                                  ushort_t* __restrict__ C, int n) {
    constexpr int NT = FOUT / 16;
    constexpr int NK = FIN / 32;
    const int wave = threadIdx.x >> 6;
    const int lane = threadIdx.x & 63;
    const int r0 = (blockIdx.x * 4 + wave) * 32;
    if (r0 >= n) return;

    const int l15 = lane & 15;
    const int kg  = lane >> 4;
    const int arow0 = min(r0 + l15, n - 1);
    const int arow1 = min(r0 + 16 + l15, n - 1);

    f32x4 acc0[NT], acc1[NT];
#pragma unroll
    for (int c = 0; c < NT; ++c) { acc0[c] = (f32x4)(0.0f); acc1[c] = (f32x4)(0.0f); }

    const ushort_t* Bp = Wt + (size_t)l15 * FIN + kg * 8;

#pragma unroll 1   // keep rolled: full unroll hoists all B loads -> spill (R1 lesson)
    for (int ks = 0; ks < NK; ++ks) {
        bf16x8 a0, a1;
        const float* p0 = A + (size_t)arow0 * FIN + kg * 8 + ks * 32;
        const float* p1 = A + (size_t)arow1 * FIN + kg * 8 + ks * 32;
        float4 u0 = *(const float4*)p0, u1 = *(const float4*)(p0 + 4);
        float4 w0 = *(const float4*)p1, w1 = *(const float4*)(p1 + 4);
        a0[0] = (short)f2bf(u0.x); a0[1] = (short)f2bf(u0.y);
        a0[2] = (short)f2bf(u0.z); a0[3] = (short)f2bf(u0.w);
        a0[4] = (short)f2bf(u1.x); a0[5] = (short)f2bf(u1.y);
        a0[6] = (short)f2bf(u1.z); a0[7] = (short)f2bf(u1.w);
        a1[0] = (short)f2bf(w0.x); a1[1] = (short)f2bf(w0.y);
        a1[2] = (short)f2bf(w0.z); a1[3] = (short)f2bf(w0.w);
        a1[4] = (short)f2bf(w1.x); a1[5] = (short)f2bf(w1.y);
        a1[6] = (short)f2bf(w1.z); a1[7] = (short)f2bf(w1.w);
#pragma unroll
        for (int c = 0; c < NT; ++c) {
            bf16x8 bfr = *(const bf16x8*)(Bp + (size_t)c * 16 * FIN + ks * 32);
            acc0[c] = __builtin_amdgcn_mfma_f32_16x16x32_bf16(a0, bfr, acc0[c], 0, 0, 0);
            acc1[c] = __builtin_amdgcn_mfma_f32_16x16x32_bf16(a1, bfr, acc1[c], 0, 0, 0);
        }
    }

#pragma unroll
    for (int g = 0; g < 2; ++g) {
        const int rbase = r0 + g * 16 + kg * 4;
#pragma unroll
        for (int j = 0; j < 4; ++j) {
            int row = rbase + j;
            if (row < n) {
                float dscale = dinv[row];
#pragma unroll
                for (int c = 0; c < NT; ++c) {
                    float val = (g == 0) ? acc0[c][j] : acc1[c][j];
                    C[(size_t)row * FOUT + c * 16 + l15] = f2bf(val * dscale);
                }
            }
        }
    }
}

// ---------------- final aggregation (layer 3, f32 out, no relu) ----------------

template <int FIN>
__global__ __launch_bounds__(256) void k_agg_final(const ushort_t* __restrict__ H,
                                                   const float* __restrict__ dinv,
                                                   const int* __restrict__ rowptr,
                                                   const int* __restrict__ csr_src,
                                                   const float* __restrict__ csr_val,
                                                   const float* __restrict__ bias,
                                                   float* __restrict__ out, int n) {
    constexpr int LPN = FIN / 8;       // 4 lanes per node
    constexpr int NPW = 64 / LPN;      // 16 nodes per wave
    const int wave = threadIdx.x >> 6;
    const int lane = threadIdx.x & 63;
    const int sub  = lane / LPN;
    const int f8   = lane % LPN;
    const int node = (blockIdx.x * 4 + wave) * NPW + sub;
    if (node >= n) return;

    const ushort_t* __restrict__ Hf = H + 8 * f8;
    const float sn = dinv[node];
    ushort8_t hv = *(const ushort8_t*)(Hf + (size_t)node * FIN);
    float a[8];
#pragma unroll
    for (int k = 0; k < 8; ++k) a[k] = sn * bf2f(hv[k]);

    agg_body<FIN>(Hf, csr_src, csr_val, rowptr[node], rowptr[node + 1], a);

    float4 bv0 = *(const float4*)(bias + 8 * f8);
    float4 bv1 = *(const float4*)(bias + 8 * f8 + 4);
    a[0] += bv0.x; a[1] += bv0.y; a[2] += bv0.z; a[3] += bv0.w;
    a[4] += bv1.x; a[5] += bv1.y; a[6] += bv1.z; a[7] += bv1.w;
    float* op = out + (size_t)node * FIN + 8 * f8;
    *(float4*)op       = make_float4(a[0], a[1], a[2], a[3]);
    *(float4*)(op + 4) = make_float4(a[4], a[5], a[6], a[7]);
}

// ---------------- launch ----------------

extern "C" void kernel_launch(void* const* d_in, const int* in_sizes, int n_in,
                              void* d_out, int out_size, void* d_ws, size_t ws_size,
                              hipStream_t stream) {
    const float* x    = (const float*)d_in[0];
    const int*   eidx = (const int*)d_in[1];
    const float* ea   = (const float*)d_in[2];
    const float* W1   = (const float*)d_in[3];
    const float* b1   = (const float*)d_in[4];
    const float* W2   = (const float*)d_in[5];
    const float* b2   = (const float*)d_in[6];
    const float* W3   = (const float*)d_in[7];
    const float* b3   = (const float*)d_in[8];

    const int N = in_sizes[0] / 128;
    const int E = in_sizes[2];

    const int nbins = (N + 255) >> BIN_SHIFT;            // 196 for N=50000 (<=256)
    const int epb   = (E + SCAT_NB - 1) / SCAT_NB;       // edges per scatter block
    const int nbc   = nbins * SCAT_NB;                   // bcnt/ebofs length
    const int gBC   = (nbc + BLK - 1) / BLK;

    char*  base = (char*)d_ws;
    size_t off  = 0;
    auto carve = [&](size_t nbytes) -> void* {
        void* p = base + off;
        off = (off + nbytes + 255) & ~(size_t)255;
        return p;
    };
    int*   bcnt      = (int*)  carve((size_t)nbc * 4);
    int*   ebofs     = (int*)  carve((size_t)nbc * 4);
    int*   bsumB     = (int*)  carve((size_t)512 * 4);
    uint2* binned    = (uint2*)carve((size_t)E * 8);
    float* dinv      = (float*)carve((size_t)N * 4);
    int*   rowptr    = (int*)  carve((size_t)(N + 1) * 4);
    int*   csr_src   = (int*)  carve((size_t)E * 4);
    float* csr_val   = (float*)carve((size_t)E * 4);
    ushort_t* bufA   = (ushort_t*)carve((size_t)N * 128 * 2);   // bf16: H'1 / H'3
    ushort_t* bufB   = (ushort_t*)carve((size_t)N * 64 * 2);    // bf16: H'2
    ushort_t* Wt1    = (ushort_t*)carve((size_t)128 * 128 * 2);
    ushort_t* Wt2    = (ushort_t*)carve((size_t)64 * 128 * 2);
    ushort_t* Wt3    = (ushort_t*)carve((size_t)32 * 64 * 2);
    (void)ws_size;

    const int wtot = 128 * 128 + 128 * 64 + 64 * 32;
    const int gPre = SCAT_NB + (wtot + 255) / 256;
    const int gR  = (N + 127) / 128;                     // gemm1 blocks (128 rows/block)
    const int gF  = (N + 31) / 32;                       // fused agg+gemm blocks (32 rows)

    // preprocessing (5 dispatches, scan-based, no global atomics)
    k_pre<<<gPre, BLK, 0, stream>>>(eidx, bcnt, nbins, epb, E, W1, Wt1, W2, Wt2, W3, Wt3);
    k_scan1<<<gBC, BLK, 0, stream>>>(bcnt, ebofs, bsumB, nbc);
    k_scan2x<<<1, BLK, 0, stream>>>(bsumB, gBC);
    k_bin_scatter<<<SCAT_NB, BLK, 0, stream>>>(eidx, ea, ebofs, bsumB, binned, nbins, epb, E);
    k_bin_finish<<<nbins, BLK, 0, stream>>>(binned, ebofs, bsumB, dinv, rowptr,
                                            csr_src, csr_val, nbins, N, E);

    // layer 1 GEMM: H'1 = dinv * (x @ W1)   (reads f32 x directly)
    k_gemm_f32<128, 128><<<gR, BLK, 0, stream>>>(x, Wt1, dinv, bufA, N);

    // fused: G2 = relu(agg(H'1)+b1); H'2 = dinv*(G2 @ W2)
    k_agg_gemm<128, 64><<<gF, BLK, 0, stream>>>(bufA, dinv, rowptr, csr_src, csr_val,
                                                b1, Wt2, bufB, N);

    // fused: G3 = relu(agg(H'2)+b2); H'3 = dinv*(G3 @ W3)
    k_agg_gemm<64, 32><<<gF, BLK, 0, stream>>>(bufB, dinv, rowptr, csr_src, csr_val,
                                               b2, Wt3, bufA, N);

    // final: out = agg(H'3) + b3   (f32, no relu)
    k_agg_final<32><<<(N + 63) / 64, BLK, 0, stream>>>(bufA, dinv, rowptr, csr_src, csr_val,
                                                       b3, (float*)d_out, N);
}